// Round 1
// baseline (1682.229 us; speedup 1.0000x reference)
//
#include <hip/hip_runtime.h>

#define IN_CAPS 1152
#define OUT_CH 32
#define BLOCK 192                                  // 3 waves; tiny LDS -> ~5 blocks/CU
#define NWAVES (BLOCK / 64)                        // 3
#define ROWS_PER_THREAD (IN_CAPS / BLOCK)          // 6
#define F4_PER_THREAD (IN_CAPS * OUT_CH / 4 / BLOCK)   // 48
#define EPS 1e-8f

__global__ __launch_bounds__(BLOCK, 4)             // cap VGPR at 128 -> 16 waves/CU
void caps_route(const float* __restrict__ u_hat,
                const float* __restrict__ c0,
                const int* __restrict__ routings_p,
                float* __restrict__ out)
{
    __shared__ float swred[NWAVES * OUT_CH];       // 384 B
    __shared__ float vsh[OUT_CH];                  // 128 B

    const int t    = threadIdx.x;
    const int n    = blockIdx.x;
    const int lane = t & 63;
    const int wave = t >> 6;

    const float4* __restrict__ u4 =
        reinterpret_cast<const float4*>(u_hat) + (size_t)n * (IN_CAPS * OUT_CH / 4);
    const float4* __restrict__ c4 = reinterpret_cast<const float4*>(c0);

    // ---------- sweep 1: s[j] = sum_i u[i,j] * c0[i,j], fully coalesced flat loads ----------
    // f = t + k*BLOCK; channel group of this thread fixed: (t&7)*4 (BLOCK % 8 == 0).
    float p0 = 0.f, p1 = 0.f, p2 = 0.f, p3 = 0.f;
    #pragma unroll
    for (int k = 0; k < F4_PER_THREAD; ++k) {
        const int f = t + k * BLOCK;
        const float4 a = u4[f];
        const float4 w = c4[f];
        p0 = fmaf(a.x, w.x, p0);
        p1 = fmaf(a.y, w.y, p1);
        p2 = fmaf(a.z, w.z, p2);
        p3 = fmaf(a.w, w.w, p3);
    }
    // lanes sharing (lane & 7) hold partials for the same 4 channels
    #pragma unroll
    for (int m = 8; m <= 32; m <<= 1) {
        p0 += __shfl_xor(p0, m);
        p1 += __shfl_xor(p1, m);
        p2 += __shfl_xor(p2, m);
        p3 += __shfl_xor(p3, m);
    }
    if (lane < 8) {
        float* dst = &swred[wave * OUT_CH + lane * 4];
        dst[0] = p0; dst[1] = p1; dst[2] = p2; dst[3] = p3;
    }
    __syncthreads();
    if (t < OUT_CH) {
        float s = 0.f;
        #pragma unroll
        for (int w = 0; w < NWAVES; ++w) s += swred[w * OUT_CH + t];
        float n2 = s * s;
        #pragma unroll
        for (int m = 1; m <= 16; m <<= 1) n2 += __shfl_xor(n2, m);
        const float scale = n2 / ((1.0f + n2) * sqrtf(n2 + EPS));
        vsh[t] = s * scale;
    }
    __syncthreads();

    // ---------- routing sweeps: re-read u from global (L2/L3-resident after sweep 1) ----------
    const int iters = routings_p[0] - 1;
    for (int it = 0; it < iters; ++it) {
        float v[OUT_CH];
        #pragma unroll
        for (int j = 0; j < OUT_CH; ++j) v[j] = vsh[j];   // broadcast LDS reads, once

        float acc[OUT_CH];
        #pragma unroll
        for (int j = 0; j < OUT_CH; ++j) acc[j] = 0.f;

        #pragma unroll
        for (int s = 0; s < ROWS_PER_THREAD; ++s) {
            const int i = t + s * BLOCK;                   // wave covers 64 contiguous rows
            const float4* __restrict__ row = u4 + i * (OUT_CH / 4);
            float rr[OUT_CH];
            #pragma unroll
            for (int k = 0; k < OUT_CH / 4; ++k) {
                const float4 q = row[k];
                rr[4*k+0] = q.x; rr[4*k+1] = q.y; rr[4*k+2] = q.z; rr[4*k+3] = q.w;
            }
            // thread-local softmax over channels; max-subtraction skipped (|u*v| small, fp32 exp safe)
            float s0 = 0.f, s1 = 0.f, s2 = 0.f, s3 = 0.f;
            #pragma unroll
            for (int j = 0; j < OUT_CH; j += 4) {
                const float e0 = __expf(rr[j+0] * v[j+0]);
                const float e1 = __expf(rr[j+1] * v[j+1]);
                const float e2 = __expf(rr[j+2] * v[j+2]);
                const float e3 = __expf(rr[j+3] * v[j+3]);
                s0 += e0; s1 += e1; s2 += e2; s3 += e3;
                rr[j+0] *= e0; rr[j+1] *= e1; rr[j+2] *= e2; rr[j+3] *= e3;
            }
            const float wr = __builtin_amdgcn_rcpf((s0 + s1) + (s2 + s3));
            #pragma unroll
            for (int j = 0; j < OUT_CH; ++j)
                acc[j] = fmaf(rr[j], wr, acc[j]);
        }

        // wave reduction: channel-split butterfly — 33 shuffles instead of 192.
        // step s (mask 1<<s): upper lane keeps upper half of its channel set,
        // receives partner's matching half. After 5 steps each lane holds ONE
        // channel (bit-reversed lane index) summed over its 32-lane group.
        #pragma unroll
        for (int st = 0; st < 5; ++st) {
            const int m    = 1 << st;
            const int half = 16 >> st;
            const bool up  = (lane & m) != 0;
            #pragma unroll
            for (int j = 0; j < half; ++j) {
                const float send = up ? acc[j] : acc[half + j];
                const float keep = up ? acc[half + j] : acc[j];
                acc[j] = keep + __shfl_xor(send, m);
            }
        }
        acc[0] += __shfl_xor(acc[0], 32);                 // combine the two 32-lane halves

        const int l5 = lane & 31;
        const int ch = ((l5 & 1) << 4) | ((l5 & 2) << 2) | (l5 & 4)
                     | ((l5 & 8) >> 2) | ((l5 & 16) >> 4);  // bitrev5
        if (lane < 32) swred[wave * OUT_CH + ch] = acc[0];  // permutation -> conflict-free
        __syncthreads();
        if (t < OUT_CH) {
            float s = 0.f;
            #pragma unroll
            for (int w = 0; w < NWAVES; ++w) s += swred[w * OUT_CH + t];
            float n2 = s * s;
            #pragma unroll
            for (int m = 1; m <= 16; m <<= 1) n2 += __shfl_xor(n2, m);
            const float scale = n2 / ((1.0f + n2) * sqrtf(n2 + EPS));
            vsh[t] = s * scale;
        }
        __syncthreads();
    }

    if (t < OUT_CH)
        out[(size_t)n * OUT_CH + t] = vsh[t] * 0.5f + 0.5f;
}

extern "C" void kernel_launch(void* const* d_in, const int* in_sizes, int n_in,
                              void* d_out, int out_size, void* d_ws, size_t ws_size,
                              hipStream_t stream) {
    const float* u_hat   = (const float*)d_in[0];
    const float* c0      = (const float*)d_in[1];
    const int*   routing = (const int*)d_in[2];
    float* out = (float*)d_out;

    const int N = in_sizes[0] / (IN_CAPS * OUT_CH);   // 4096
    caps_route<<<dim3(N), dim3(BLOCK), 0, stream>>>(u_hat, c0, routing, out);
}